// Round 1
// baseline (80.954 us; speedup 1.0000x reference)
//
#include <hip/hip_runtime.h>

#define BN 200
#define KK 32
#define HH 138
#define WW 138
#define HO 550
#define WO 550
#define NPIX (HH*WW)      // 19044
#define NOUT (HO*WO)      // 302500
#define EPS 1e-6f

// ---------------- Kernel 1: fused gaussian * sigmoid(proto.mask) * conf
// -> final_conf [B, HH, WW] --------------------------------------------
__global__ __launch_bounds__(256) void k_finalconf(
    const float* __restrict__ loc,    // [B,200,4] (cx,cy,sx,sy)
    const float* __restrict__ conf,   // [B,200]
    const float* __restrict__ mask,   // [B,200,32]
    const float* __restrict__ proto,  // [B,138,138,32]
    float* __restrict__ fconf)        // [B,138,138]
{
    const int b   = blockIdx.y;
    const int tid = threadIdx.x;

    __shared__ float sm_mask[BN * KK];
    __shared__ float sm_cx[BN], sm_cy[BN], sm_isx[BN], sm_isy[BN], sm_cf[BN];

    // cooperative staging of per-batch params
    const float4* mb = (const float4*)(mask + (size_t)b * BN * KK);
    for (int i = tid; i < BN * KK / 4; i += 256)
        ((float4*)sm_mask)[i] = mb[i];

    const float4* lb = (const float4*)(loc + (size_t)b * BN * 4);
    const float*  cb = conf + (size_t)b * BN;
    for (int n = tid; n < BN; n += 256) {
        float4 l = lb[n];
        sm_cx[n]  = l.x;
        sm_cy[n]  = l.y;
        sm_isx[n] = __frcp_rn(l.z);
        sm_isy[n] = __frcp_rn(l.w);
        sm_cf[n]  = cb[n];
    }
    __syncthreads();

    const int pix = blockIdx.x * 256 + tid;
    if (pix >= NPIX) return;
    const int h = pix / WW;
    const int w = pix - h * WW;
    const float x = (w + 0.5f) * (1.0f / WW);
    const float y = (h + 0.5f) * (1.0f / HH);

    // proto fragment for this pixel: 32 floats in registers
    float4 p[8];
    const float4* pb = (const float4*)(proto + ((size_t)b * NPIX + pix) * KK);
#pragma unroll
    for (int i = 0; i < 8; ++i) p[i] = pb[i];

    float sum1 = 0.0f, sum2 = 0.0f;
    for (int n = 0; n < BN; ++n) {
        const float4* m4 = (const float4*)(sm_mask + n * KK);
        float s = 0.0f;
#pragma unroll
        for (int i = 0; i < 8; ++i) {
            float4 m = m4[i];
            s = fmaf(p[i].x, m.x, s);
            s = fmaf(p[i].y, m.y, s);
            s = fmaf(p[i].z, m.z, s);
            s = fmaf(p[i].w, m.w, s);
        }
        // sigmoid
        float a = __frcp_rn(1.0f + __expf(-s));
        // gaussian (separable form inline)
        float dx = (x - sm_cx[n]) * sm_isx[n];
        float dy = (y - sm_cy[n]) * sm_isy[n];
        float g  = __expf(-0.5f * fmaf(dx, dx, dy * dy));
        float mc = a * g * sm_cf[n];
        sum1 += mc;
        sum2 = fmaf(mc, mc, sum2);
    }
    fconf[(size_t)b * NPIX + pix] = 1.0f - sum2 / (sum1 + EPS);
}

// ---------------- Kernel 2: bilinear upsample + weighted variance,
// per-block partial sums --------------------------------------------------
__global__ __launch_bounds__(256) void k_variance(
    const float* __restrict__ orig,   // [B,3,550,550]
    const float* __restrict__ fconf,  // [B,138,138]
    float* __restrict__ partial)      // [gridDim.x]
{
    const int idx = blockIdx.x * 256 + threadIdx.x;
    float local = 0.0f;

    if (idx < NOUT) {
        const int yo = idx / WO;
        const int xo = idx - yo * WO;
        const float scale = 138.0f / 550.0f;
        float fy = (yo + 0.5f) * scale - 0.5f;
        float fx = (xo + 0.5f) * scale - 0.5f;
        float fy0 = floorf(fy), fx0 = floorf(fx);
        float wy = fy - fy0, wx = fx - fx0;
        int y0 = max(0, min(HH - 1, (int)fy0));
        int y1 = max(0, min(HH - 1, (int)fy0 + 1));
        int x0 = max(0, min(WW - 1, (int)fx0));
        int x1 = max(0, min(WW - 1, (int)fx0 + 1));

        float R[8];
        float T = 0.0f;
#pragma unroll
        for (int b = 0; b < 8; ++b) {
            const float* F = fconf + (size_t)b * NPIX;
            float v00 = F[y0 * WW + x0], v01 = F[y0 * WW + x1];
            float v10 = F[y1 * WW + x0], v11 = F[y1 * WW + x1];
            float v0 = v00 + wx * (v01 - v00);
            float v1 = v10 + wx * (v11 - v10);
            R[b] = v0 + wy * (v1 - v0);
            T += R[b];
        }
        const float invT = __frcp_rn(T + EPS);

#pragma unroll
        for (int c = 0; c < 3; ++c) {
            float o[8];
            float M = 0.0f;
#pragma unroll
            for (int b = 0; b < 8; ++b) {
                o[b] = orig[((size_t)b * 3 + c) * NOUT + idx];
                M = fmaf(o[b], R[b], M);
            }
            float s = 0.0f;
#pragma unroll
            for (int b = 0; b < 8; ++b) {
                float d = o[b] - M;
                s = fmaf(d * d, R[b], s);
            }
            local += s * invT;
        }
    }

    // deterministic block reduction
    __shared__ float red[4];
    const int lane = threadIdx.x & 63;
    const int wid  = threadIdx.x >> 6;
#pragma unroll
    for (int off = 32; off > 0; off >>= 1)
        local += __shfl_down(local, off);
    if (lane == 0) red[wid] = local;
    __syncthreads();
    if (threadIdx.x == 0)
        partial[blockIdx.x] = (red[0] + red[1]) + (red[2] + red[3]);
}

// ---------------- Kernel 3: deterministic final reduce -------------------
__global__ __launch_bounds__(256) void k_reduce(
    const float* __restrict__ partial, int n, float* __restrict__ out)
{
    float s = 0.0f;
    for (int i = threadIdx.x; i < n; i += 256) s += partial[i];
    __shared__ float red[4];
    const int lane = threadIdx.x & 63;
    const int wid  = threadIdx.x >> 6;
#pragma unroll
    for (int off = 32; off > 0; off >>= 1)
        s += __shfl_down(s, off);
    if (lane == 0) red[wid] = s;
    __syncthreads();
    if (threadIdx.x == 0)
        out[0] = (red[0] + red[1]) + (red[2] + red[3]);
}

extern "C" void kernel_launch(void* const* d_in, const int* in_sizes, int n_in,
                              void* d_out, int out_size, void* d_ws, size_t ws_size,
                              hipStream_t stream) {
    const float* original = (const float*)d_in[0];  // [8,3,550,550]
    const float* loc      = (const float*)d_in[1];  // [8,200,4]
    const float* conf     = (const float*)d_in[2];  // [8,200]
    const float* mask     = (const float*)d_in[3];  // [8,200,32]
    const float* proto    = (const float*)d_in[4];  // [8,138,138,32]
    float* out = (float*)d_out;

    float* fconf   = (float*)d_ws;                                   // 8*138*138 f32 = 609 KB
    float* partial = (float*)((char*)d_ws + (size_t)8 * NPIX * sizeof(float));

    dim3 g1((NPIX + 255) / 256, 8);
    k_finalconf<<<g1, 256, 0, stream>>>(loc, conf, mask, proto, fconf);

    const int nb2 = (NOUT + 255) / 256;   // 1182
    k_variance<<<nb2, 256, 0, stream>>>(original, fconf, partial);

    k_reduce<<<1, 256, 0, stream>>>(partial, nb2, out);
}